// Round 1
// baseline (412.857 us; speedup 1.0000x reference)
//
#include <hip/hip_runtime.h>
#include <math.h>

// FCNNSlopeValuationFunction: per-row angle -> zone -> gather dir[row, zone],
// masked by z_1[:,0] != 0.
//
// Numerics strategy (must match numpy-f32 reference bit-for-bit at truncation
// boundaries):
//  - Zone is a pure function of t = int(phi_ref) (everything downstream is
//    integer-exact; ((pcs+11)/22 in f32).floor == integer (pcs+11)/22 for
//    pcs in [0,359] — quotient <= 17, no half-ulp-crossing cases exist).
//  - Fast path: ocml atan2f (<=6 ulp => error <= ~1e-4 deg after degrees
//    multiply). Evaluate zone at floor(phi +/- EPS), EPS = 2^-7 deg (~80x the
//    error bound). If both probes give the same zone, that zone is provably
//    the reference's (phi_ref lies inside the probe interval; interval < 1 deg
//    so t_ref takes at most the two probed values). Wrap at 0/360 is handled
//    in mod-360 t-space, where zone is continuous (t=360 == t=0 via pcs).
//  - Slow path (p ~= 0.07% of lanes: interval straddles one of the ~16
//    zone-boundary integers): exact recompute = correctly-rounded f32 atan2
//    via double, f32 degrees multiply, no fma contraction — the previously
//    verified-exact path.
//  - dir row (32B) is loaded with two coalesced dwordx4 *before* the atan
//    chain (no dependent gather round-trip); selected with a cndmask tree.

__device__ __forceinline__ int zone_of(int t) {
    // t in [0, 360]; pcs = (90 + t) % 360; zone = ((pcs + 11) / 22) % 8
    int pcs = 90 + t;
    if (pcs >= 360) pcs -= 360;
    return ((pcs + 11) / 22) & 7;
}

__global__ __launch_bounds__(256) void slope_zone_kernel(
    const float* __restrict__ z1,
    const float* __restrict__ dir,
    float* __restrict__ out,
    int n)
{
#pragma clang fp contract(off)
    int i = blockIdx.x * blockDim.x + threadIdx.x;
    if (i >= n) return;

    // z_1 row: 16 floats, 64B-aligned. Need cols 0..4.
    const float4* zrow = reinterpret_cast<const float4*>(z1 + (size_t)i * 16);
    float4 a = zrow[0];                       // x=line, y=lx, z=ly, w=rx
    float ry = z1[(size_t)i * 16 + 4];

    // Issue the full dir row load NOW (independent of the atan chain):
    // two coalesced dwordx4 instead of a dependent 4B gather.
    const float4* drow = reinterpret_cast<const float4*>(dir + (size_t)i * 8);
    float4 d0 = drow[0];
    float4 d1 = drow[1];

    float dx = a.w - a.y;                     // rx - lx   (f32, matches ref)
    float dy = -(ry - a.z);                   // -(ry - ly) incl. signed-zero

    // ---- fast path: f32 atan2, zone probed at +/- EPS ----
    float pf = atan2f(dy, dx) * 57.29577951308232f;
    if (pf < 0.0f) pf = 360.0f + pf;          // pf in [0, 360]

    const float EPS = 0.0078125f;             // 2^-7 deg; fast-path err <~1e-4
    int t_lo = (int)floorf(pf - EPS);         // may be -1 near 0
    int t_hi = (int)floorf(pf + EPS);         // may be 360 near 360
    if (t_lo < 0) t_lo += 360;                // zone continuous across wrap
    int zone = zone_of(t_lo);
    if (zone != zone_of(t_hi)) {
        // ---- slow path (rare): exact, matches reference bit-for-bit ----
        // correctly-rounded f32 atan2 via double == numpy's atan2f
        float phi_rad = (float)atan2((double)dy, (double)dx);
        // numpy degrees: single f32 multiply by f32-rounded 180/pi (no fma)
        float phi = phi_rad * 57.29577951308232f;
        if (phi < 0.0f) phi = 360.0f + phi;   // f32 add, matches ref
        zone = zone_of((int)phi);             // trunc == floor (phi >= 0)
    }

    // select dir[zone] from registers: 7 cndmasks
    float e0 = (zone & 1) ? d0.y : d0.x;
    float e1 = (zone & 1) ? d0.w : d0.z;
    float e2 = (zone & 1) ? d1.y : d1.x;
    float e3 = (zone & 1) ? d1.w : d1.z;
    float f0 = (zone & 2) ? e1 : e0;
    float f1 = (zone & 2) ? e3 : e2;
    float g  = (zone & 4) ? f1 : f0;

    out[i] = (a.x != 0.0f) ? g : 0.0f;
}

extern "C" void kernel_launch(void* const* d_in, const int* in_sizes, int n_in,
                              void* d_out, int out_size, void* d_ws, size_t ws_size,
                              hipStream_t stream) {
    const float* z1  = (const float*)d_in[0];   // (B,16) f32
    const float* dir = (const float*)d_in[1];   // (B,8)  f32
    float* out = (float*)d_out;                 // (B,)   f32
    int n = out_size;
    int threads = 256;
    int blocks = (n + threads - 1) / threads;
    hipLaunchKernelGGL(slope_zone_kernel, dim3(blocks), dim3(threads), 0, stream,
                       z1, dir, out, n);
}